// Round 2
// baseline (13869.737 us; speedup 1.0000x reference)
//
#include <hip/hip_runtime.h>
#include <hip/hip_bf16.h>

#define B_  64
#define S_  1024
#define I_  512
#define H_  512
#define G4  2048   // 4*H
#define KTOT 1024  // I_ + H_
#define NBLK 128   // persistent grid: 32 jb x 4 bb

typedef float f32x4 __attribute__((ext_vector_type(4)));
typedef short s16x8 __attribute__((ext_vector_type(8)));

__device__ inline ushort f2bf(float f) {
    union { __hip_bfloat16 h; ushort u; } v;
    v.h = __float2bfloat16(f);
    return v.u;
}

__device__ inline float sig_f(float x) { return 1.f / (1.f + __expf(-x)); }
__device__ inline float tanh_f(float x) { return 1.f - 2.f / (1.f + __expf(2.f * x)); }

// L3-direct (agent-coherent) 16B load of h, bypassing stale L1/L2.
__device__ inline s16x8 load_h16(const ushort* p) {
    unsigned long long lo = __hip_atomic_load((const unsigned long long*)p,
                                              __ATOMIC_RELAXED, __HIP_MEMORY_SCOPE_AGENT);
    unsigned long long hi = __hip_atomic_load((const unsigned long long*)(p + 4),
                                              __ATOMIC_RELAXED, __HIP_MEMORY_SCOPE_AGENT);
    union { unsigned long long q[2]; s16x8 v; } u;
    u.q[0] = lo; u.q[1] = hi;
    return u.v;
}

// WUt[g][k] = (k<512 ? W[k][g] : U[k-512][g]) as bf16.  [2048][1024]
__global__ __launch_bounds__(1024) void prep_wut(const float* __restrict__ W,
                                                 const float* __restrict__ U,
                                                 ushort* __restrict__ WUt) {
    __shared__ ushort lds[32][33];
    int g0 = blockIdx.x * 32, k0 = blockIdx.y * 32;
    int tx = threadIdx.x, ty = threadIdx.y;
    int k = k0 + ty, g = g0 + tx;
    float v = (k < I_) ? W[(size_t)k * G4 + g] : U[(size_t)(k - I_) * G4 + g];
    lds[ty][tx] = f2bf(v);
    __syncthreads();
    WUt[(size_t)(g0 + ty) * KTOT + k0 + tx] = lds[tx][ty];
}

// x fp32 -> bf16, 8 elements/thread
__global__ __launch_bounds__(256) void prep_xbf(const float* __restrict__ x,
                                                ushort* __restrict__ xbf) {
    size_t i = ((size_t)blockIdx.x * 256 + threadIdx.x) * 8;
    float4 a = *(const float4*)(x + i);
    float4 b = *(const float4*)(x + i + 4);
    union { ushort u[8]; s16x8 v; } o;
    o.u[0] = f2bf(a.x); o.u[1] = f2bf(a.y); o.u[2] = f2bf(a.z); o.u[3] = f2bf(a.w);
    o.u[4] = f2bf(b.x); o.u[5] = f2bf(b.y); o.u[6] = f2bf(b.z); o.u[7] = f2bf(b.w);
    *(s16x8*)(xbf + i) = o.v;
}

__global__ void init_cnt(int* cnt) { *cnt = 0; }

// Persistent LSTM: 128 blocks x 256 threads (4 waves = 4 gates).
// Block (bb,jb) owns batch rows [bb*16,+16) and hidden cols [jb*16,+16).
// Weights held in VGPRs; c held in registers; h exchanged via L3-coherent ws.
template <bool XBF>
__global__ __launch_bounds__(256, 1) void lstm_persist(
    const float* __restrict__ x32, const ushort* __restrict__ xbf,
    const float* __restrict__ bias, const ushort* __restrict__ WUt,
    ushort* __restrict__ h0, ushort* __restrict__ h1,
    int* __restrict__ cnt, float* __restrict__ out)
{
    __shared__ float glds[4][16][17];
    const int jb = blockIdx.x & 31;
    const int bb = blockIdx.x >> 5;
    const int tid = threadIdx.x;
    const int w = tid >> 6, lane = tid & 63;
    const int m = lane & 15, q = lane >> 4;     // frag: row/col m, k = q*8+..
    const int b = bb * 16 + m;

    // Load this wave's weight slice into registers: 16 cols x 1024 K of bf16.
    const ushort* brow = WUt + (size_t)(w * H_ + jb * 16 + m) * KTOT;
    s16x8 wfrag[32];
    #pragma unroll
    for (int kk = 0; kk < 32; ++kk)
        wfrag[kk] = *(const s16x8*)(brow + kk * 32 + q * 8);

    // epilogue mapping
    const int bl = tid >> 4, jl = tid & 15;
    const int j = jb * 16 + jl;
    const int bg = bb * 16 + bl;
    const float b_i = bias[j], b_f = bias[H_ + j];
    const float b_g = bias[2 * H_ + j], b_o = bias[3 * H_ + j];
    float creg = 0.f;
    float hv = 0.f;

    ushort* hb[2] = {h0, h1};
    const float*  x32row = x32 + (size_t)b * S_ * I_;
    const ushort* xbfrow = xbf + (size_t)b * S_ * I_;

    for (int t = 0; t < S_; ++t) {
        f32x4 a0 = {0.f,0.f,0.f,0.f}, a1 = a0, a2 = a0, a3 = a0;

        // ---- x_t @ W  (K = 0..511) ----
        if (XBF) {
            const ushort* xr = xbfrow + (size_t)t * I_;
            #pragma unroll
            for (int kk = 0; kk < 16; ++kk) {
                s16x8 a = *(const s16x8*)(xr + kk * 32 + q * 8);
                f32x4& ac = (kk & 3) == 0 ? a0 : (kk & 3) == 1 ? a1 : (kk & 3) == 2 ? a2 : a3;
                ac = __builtin_amdgcn_mfma_f32_16x16x32_bf16(a, wfrag[kk], ac, 0, 0, 0);
            }
        } else {
            const float* xr = x32row + (size_t)t * I_;
            #pragma unroll
            for (int kk = 0; kk < 16; ++kk) {
                int k0 = kk * 32 + q * 8;
                float4 xa = *(const float4*)(xr + k0);
                float4 xb = *(const float4*)(xr + k0 + 4);
                s16x8 a;
                a[0] = (short)f2bf(xa.x); a[1] = (short)f2bf(xa.y);
                a[2] = (short)f2bf(xa.z); a[3] = (short)f2bf(xa.w);
                a[4] = (short)f2bf(xb.x); a[5] = (short)f2bf(xb.y);
                a[6] = (short)f2bf(xb.z); a[7] = (short)f2bf(xb.w);
                f32x4& ac = (kk & 3) == 0 ? a0 : (kk & 3) == 1 ? a1 : (kk & 3) == 2 ? a2 : a3;
                ac = __builtin_amdgcn_mfma_f32_16x16x32_bf16(a, wfrag[kk], ac, 0, 0, 0);
            }
        }

        // ---- h_{t-1} @ U  (K = 512..1023), skip at t=0 (h0 = 0) ----
        if (t > 0) {
            const ushort* hr = hb[t & 1] + b * H_;
            #pragma unroll
            for (int kk = 0; kk < 16; ++kk) {
                s16x8 a = load_h16(hr + kk * 32 + q * 8);
                f32x4& ac = (kk & 3) == 0 ? a0 : (kk & 3) == 1 ? a1 : (kk & 3) == 2 ? a2 : a3;
                ac = __builtin_amdgcn_mfma_f32_16x16x32_bf16(a, wfrag[16 + kk], ac, 0, 0, 0);
            }
        }

        f32x4 acc = a0 + a1 + a2 + a3;
        // C/D layout: col = lane&15, row = q*4+r
        #pragma unroll
        for (int r = 0; r < 4; ++r) glds[w][q * 4 + r][m] = acc[r];
        __syncthreads();

        // ---- gates + state update (1 (b,j) per thread) ----
        float gi = glds[0][bl][jl] + b_i;
        float gf = glds[1][bl][jl] + b_f;
        float gg = glds[2][bl][jl] + b_g;
        float go = glds[3][bl][jl] + b_o;
        float iv = sig_f(gi), fv = sig_f(gf), gv = tanh_f(gg), ov = sig_f(go);
        creg = fv * creg + iv * gv;
        hv = ov * tanh_f(creg);

        // h_next via L3-direct store (visible device-wide after vmcnt drain)
        __hip_atomic_store(&hb[(t + 1) & 1][bg * H_ + j], f2bf(hv),
                           __ATOMIC_RELAXED, __HIP_MEMORY_SCOPE_AGENT);
        __builtin_nontemporal_store(hv, &out[((size_t)bg * S_ + t) * H_ + j]);

        // ---- device barrier: syncthreads drains stores (vmcnt0), then arrive ----
        __syncthreads();
        if (tid == 0) {
            __hip_atomic_fetch_add(cnt, 1, __ATOMIC_ACQ_REL, __HIP_MEMORY_SCOPE_AGENT);
            const int target = (t + 1) * NBLK;
            while (__hip_atomic_load(cnt, __ATOMIC_ACQUIRE, __HIP_MEMORY_SCOPE_AGENT) < target)
                __builtin_amdgcn_s_sleep(1);
        }
        __syncthreads();
    }

    // h_t and c_t
    out[(size_t)B_ * S_ * H_ + bg * H_ + j] = hv;
    out[(size_t)B_ * S_ * H_ + (size_t)B_ * H_ + bg * H_ + j] = creg;
}

extern "C" void kernel_launch(void* const* d_in, const int* in_sizes, int n_in,
                              void* d_out, int out_size, void* d_ws, size_t ws_size,
                              hipStream_t stream) {
    const float* x    = (const float*)d_in[0];
    const float* W    = (const float*)d_in[1];
    const float* U    = (const float*)d_in[2];
    const float* bias = (const float*)d_in[3];
    float* out = (float*)d_out;
    char* ws = (char*)d_ws;

    // ws layout:
    int*    cnt = (int*)ws;                                  // 256 B
    ushort* h0  = (ushort*)(ws + 256);                       // 64 KiB
    ushort* h1  = h0 + B_ * H_;                              // 64 KiB
    size_t  woff = 256 + (size_t)2 * B_ * H_ * sizeof(ushort);
    ushort* WUt = (ushort*)(ws + woff);                      // 4 MiB
    size_t  xoff = woff + (size_t)G4 * KTOT * sizeof(ushort);
    ushort* xbf = (ushort*)(ws + xoff);                      // 64 MiB (optional)
    size_t  need_xbf = xoff + (size_t)B_ * S_ * I_ * sizeof(ushort);
    bool use_xbf = (ws_size >= need_xbf);

    init_cnt<<<1, 1, 0, stream>>>(cnt);
    prep_wut<<<dim3(G4 / 32, KTOT / 32), dim3(32, 32), 0, stream>>>(W, U, WUt);
    if (use_xbf) {
        prep_xbf<<<(B_ * S_ * I_) / (256 * 8), 256, 0, stream>>>(x, xbf);
        lstm_persist<true><<<NBLK, 256, 0, stream>>>(x, xbf, bias, WUt, h0, h1, cnt, out);
    } else {
        lstm_persist<false><<<NBLK, 256, 0, stream>>>(x, xbf, bias, WUt, h0, h1, cnt, out);
    }
}